// Round 6
// baseline (337.009 us; speedup 1.0000x reference)
//
#include <hip/hip_runtime.h>

// Pure permutation kernel for KernelActivation (k=2), LDS-staged,
// issue-minimized version.
//
// Mapping: out_flat[ (((b*32+i)*112 + j)*224 + w)*4 + p*2 + q ] = x[b, 2i+p, 2j+q, w]
//
// Insight from R5 counters: previous versions were INSTRUCTION-ISSUE bound
// (~19 instrs per 32 B moved -> ~4 TB/s ceiling; measured 103 us matches),
// not HBM bound. This version uses BLOCK=448 (= 2*224) so that:
//   - tid = j_half*224 + w  directly; output index = tile_base + tid + k*448
//     (contiguous stores, constant-stride pointer, no div/mod in the loop)
//   - all 16 LDS reads per thread share ONE vaddr with compile-time
//     immediate offsets (ds_read_b32 offset:N, max 25984 B < 64 KiB)
//   - load phase is 4 exact-fit float4 copies (448*4 = 1792), no selects
// ~9 instrs per 32 B moved -> issue ceiling ~8.7 TB/s; kernel becomes
// HBM-limited (~65-80 us for 308 MB actual HBM traffic).

typedef float float4n __attribute__((ext_vector_type(4)));

constexpr int Wd = 224;
constexpr int Hd = 224;
constexpr int Cd = 64;
constexpr int HALF_H = Hd / 2;            // 112
constexpr int HALF_C = Cd / 2;            // 32
constexpr int TJ = 8;                     // j-values per block
constexpr int ROWS = 2 * TJ;              // 16 input h-rows per chunk
constexpr int CHUNK_F = ROWS * Wd;        // 3584 floats = 14 KB per chunk
constexpr int CHUNK_F4 = CHUNK_F / 4;     // 896
constexpr int TILE_F4 = 2 * CHUNK_F4;     // 1792
constexpr int BLOCK = 448;                // 7 waves; tid = j_half*224 + w

__global__ __launch_bounds__(BLOCK)
void permute_kernel(const float* __restrict__ x, float4n* __restrict__ out) {
    __shared__ float lds[2 * CHUNK_F];    // 28 KB
    float4n* lds4 = reinterpret_cast<float4n*>(lds);

    const int tile = blockIdx.x;
    const int jb = tile % (HALF_H / TJ);  // 0..13
    const int u  = tile / (HALF_H / TJ);
    const int i  = u % HALF_C;
    const int b  = u / HALF_C;
    const int j0 = jb * TJ;

    const int tid = threadIdx.x;

    // Input chunks: rows h in [2*j0, 2*j0+16) of channels 2i and 2i+1.
    const float4n* __restrict__ src0 =
        reinterpret_cast<const float4n*>(x + (((size_t)(b * Cd + 2 * i)     * Hd + 2 * j0) * Wd));
    const float4n* __restrict__ src1 =
        reinterpret_cast<const float4n*>(x + (((size_t)(b * Cd + 2 * i + 1) * Hd + 2 * j0) * Wd));

    // ---- Load phase: 4 exact-fit float4 copies (448 threads x 4 = 1792).
    lds4[tid            ] = src0[tid];
    lds4[tid +     BLOCK] = src0[tid + BLOCK];
    lds4[tid + 2 * BLOCK] = src1[tid];
    lds4[tid + 3 * BLOCK] = src1[tid + BLOCK];
    __syncthreads();

    // ---- Store phase: 4 iterations, each: 4 ds_read_b32 (one shared vaddr,
    // immediate offsets) + 1 contiguous dwordx4 store.
    // tid = j_half*224 + w ; jl = 2k + j_half ; LDS row r = 2*jl + q.
    const int j_half = (tid >= Wd) ? 1 : 0;
    const int base = tid + j_half * Wd;   // = 2*j_half*224 + w

    float4n* __restrict__ dst =
        out + (((size_t)(b * HALF_C + i) * HALF_H + j0) * Wd) + tid;

    #pragma unroll
    for (int k = 0; k < 4; ++k) {
        const int o = base + k * 4 * Wd;  // k*896 floats = 3584 B imm steps
        float4n v;
        v.x = lds[o];                      // c=2i,   h=2j   (r=4k+2jh)
        v.y = lds[o + Wd];                 // c=2i,   h=2j+1
        v.z = lds[o + CHUNK_F];            // c=2i+1, h=2j
        v.w = lds[o + CHUNK_F + Wd];       // c=2i+1, h=2j+1
        dst[k * BLOCK] = v;
    }
}

extern "C" void kernel_launch(void* const* d_in, const int* in_sizes, int n_in,
                              void* d_out, int out_size, void* d_ws, size_t ws_size,
                              hipStream_t stream) {
    const float* x = (const float*)d_in[0];
    float4n* out = (float4n*)d_out;

    const int Bn = out_size / (Cd * Hd * Wd);          // 16
    const int grid = Bn * HALF_C * (HALF_H / TJ);      // 16*32*14 = 7168

    permute_kernel<<<grid, BLOCK, 0, stream>>>(x, out);
}

// Round 7
// 322.371 us; speedup vs baseline: 1.0454x; 1.0454x over previous
//
#include <hip/hip_runtime.h>

// Pure permutation kernel for KernelActivation (k=2), LDS-staged,
// issue-minimized version + NONTEMPORAL hints restored.
//
// Mapping: out_flat[ (((b*32+i)*112 + j)*224 + w)*4 + p*2 + q ] = x[b, 2i+p, 2j+q, w]
//
// R6 post-mortem: dropping __builtin_nontemporal_* regressed +12.6 us.
// Mechanism: without nt, the 205 MB store stream allocates in L2/L3 and
// evicts the ~50% L3-resident input (R4 profile: FETCH=103 MB of 205 MB),
// adding ~100 MB of HBM fetch (~+16 us at 6.3 TB/s). nt stores bypass
// cache allocation; the input's L3 residency is preserved.
//
// Structure (unchanged from R6): BLOCK=448 (= 2*224) so that
//   - output index = tile_base + tid + k*448 (contiguous, no div/mod)
//   - all 16 LDS reads per thread share ONE vaddr, immediate offsets
//   - load phase is 4 exact-fit float4 copies (448*4 = 1792), no selects

typedef float float4n __attribute__((ext_vector_type(4)));

constexpr int Wd = 224;
constexpr int Hd = 224;
constexpr int Cd = 64;
constexpr int HALF_H = Hd / 2;            // 112
constexpr int HALF_C = Cd / 2;            // 32
constexpr int TJ = 8;                     // j-values per block
constexpr int ROWS = 2 * TJ;              // 16 input h-rows per chunk
constexpr int CHUNK_F = ROWS * Wd;        // 3584 floats = 14 KB per chunk
constexpr int BLOCK = 448;                // 7 waves; tid = j_half*224 + w

__global__ __launch_bounds__(BLOCK)
void permute_kernel(const float* __restrict__ x, float4n* __restrict__ out) {
    __shared__ float lds[2 * CHUNK_F];    // 28 KB
    float4n* lds4 = reinterpret_cast<float4n*>(lds);

    const int tile = blockIdx.x;
    const int jb = tile % (HALF_H / TJ);  // 0..13
    const int u  = tile / (HALF_H / TJ);
    const int i  = u % HALF_C;
    const int b  = u / HALF_C;
    const int j0 = jb * TJ;

    const int tid = threadIdx.x;

    // Input chunks: rows h in [2*j0, 2*j0+16) of channels 2i and 2i+1.
    const float4n* __restrict__ src0 =
        reinterpret_cast<const float4n*>(x + (((size_t)(b * Cd + 2 * i)     * Hd + 2 * j0) * Wd));
    const float4n* __restrict__ src1 =
        reinterpret_cast<const float4n*>(x + (((size_t)(b * Cd + 2 * i + 1) * Hd + 2 * j0) * Wd));

    // ---- Load phase: 4 exact-fit nontemporal float4 copies (448*4 = 1792).
    lds4[tid            ] = __builtin_nontemporal_load(&src0[tid]);
    lds4[tid +     BLOCK] = __builtin_nontemporal_load(&src0[tid + BLOCK]);
    lds4[tid + 2 * BLOCK] = __builtin_nontemporal_load(&src1[tid]);
    lds4[tid + 3 * BLOCK] = __builtin_nontemporal_load(&src1[tid + BLOCK]);
    __syncthreads();

    // ---- Store phase: 4 iterations, each: 4 ds_read_b32 (one shared vaddr,
    // immediate offsets) + 1 contiguous nontemporal dwordx4 store.
    // tid = j_half*224 + w ; jl = 2k + j_half ; LDS row r = 2*jl + q.
    const int j_half = (tid >= Wd) ? 1 : 0;
    const int base = tid + j_half * Wd;   // = 2*j_half*224 + w

    float4n* __restrict__ dst =
        out + (((size_t)(b * HALF_C + i) * HALF_H + j0) * Wd) + tid;

    #pragma unroll
    for (int k = 0; k < 4; ++k) {
        const int o = base + k * 4 * Wd;  // k*896 floats = 3584 B imm steps
        float4n v;
        v.x = lds[o];                      // c=2i,   h=2j
        v.y = lds[o + Wd];                 // c=2i,   h=2j+1
        v.z = lds[o + CHUNK_F];            // c=2i+1, h=2j
        v.w = lds[o + CHUNK_F + Wd];       // c=2i+1, h=2j+1
        __builtin_nontemporal_store(v, &dst[k * BLOCK]);
    }
}

extern "C" void kernel_launch(void* const* d_in, const int* in_sizes, int n_in,
                              void* d_out, int out_size, void* d_ws, size_t ws_size,
                              hipStream_t stream) {
    const float* x = (const float*)d_in[0];
    float4n* out = (float4n*)d_out;

    const int Bn = out_size / (Cd * Hd * Wd);          // 16
    const int grid = Bn * HALF_C * (HALF_H / TJ);      // 16*32*14 = 7168

    permute_kernel<<<grid, BLOCK, 0, stream>>>(x, out);
}